// Round 6
// baseline (104.979 us; speedup 1.0000x reference)
//
#include <hip/hip_runtime.h>
#include <hip/hip_bf16.h>
#include <stdint.h>

typedef __attribute__((ext_vector_type(4))) float f32x4;
typedef __attribute__((ext_vector_type(8))) short bf16x8;
typedef __attribute__((ext_vector_type(4))) uint32_t u32x4;

#define NCH 21
#define NROW 256
#define DIM 4096
#define BM 64
#define BK 64
#define LDSS 72  // row stride in ushorts: 144 B (16B-aligned, odd multiple of 16 -> spread bank quads)

__device__ __forceinline__ uint32_t pack_bf2(float x, float y) {
  __hip_bfloat162 h = __float22bfloat162_rn(float2{x, y});  // v_cvt_pk_bf16_f32 (m240: use the cast)
  union { __hip_bfloat162 h; uint32_t u; } c;
  c.h = h;
  return c.u;
}

// ---------------------------------------------------------------------------
// Partial Gram: Gp[ch,ks] = Tb[ch][:, ks*kchunk:(ks+1)*kchunk] * (same)^T
// 64x64 tile / block, 4 waves x (2x2 frags of mfma_f32_16x16x32_bf16).
// Single LDS buffer, 2 barriers/iter (m114: TLP from 8 resident blocks/CU
// does the overlap; m99/m100: explicit dbuf is null and halves blocks/CU).
// P=8 K-split oversubscribes: 2688 blocks -> 10.5 demanded vs 8 LDS-capped.
// ---------------------------------------------------------------------------
__global__ __launch_bounds__(256) void gram_kernel(
    const float* __restrict__ src, const float* __restrict__ tgt,
    float* __restrict__ Gp, int kshift, int kchunk) {
  const int bz = blockIdx.z;
  const int ch = bz >> kshift;
  const int ks = bz & ((1 << kshift) - 1);
  const int kbase = ks * kchunk;
  const int ti = blockIdx.y;
  const int tj = blockIdx.x;
  const int tid = threadIdx.x;
  const int lane = tid & 63;

  __shared__ __attribute__((aligned(16))) ushort As[BM * LDSS];
  __shared__ __attribute__((aligned(16))) ushort Bs[BM * LDSS];

  f32x4 acc[2][2];
#pragma unroll
  for (int m = 0; m < 2; ++m)
#pragma unroll
    for (int n = 0; n < 2; ++n)
      acc[m][n] = (f32x4){0.f, 0.f, 0.f, 0.f};

  const int wave = tid >> 6;
  const int wrow = (wave >> 1) * 32;
  const int wcol = (wave & 1) * 32;

  // staging geometry: rows r0 and r0+32, 8 floats starting at column c8
  const int r0 = tid >> 3;          // 0..31
  const int c8 = (tid & 7) * 8;     // 0,8,...,56
  const float* ap[2];
  const float* bp[2];
#pragma unroll
  for (int p = 0; p < 2; ++p) {
    int ra = ti * BM + r0 + p * 32;
    int rb = tj * BM + r0 + p * 32;
    ap[p] = ((ra < 128) ? src + ((size_t)ra * NCH + ch) * DIM
                        : tgt + ((size_t)(ra - 128) * NCH + ch) * DIM) + c8;
    bp[p] = ((rb < 128) ? src + ((size_t)rb * NCH + ch) * DIM
                        : tgt + ((size_t)(rb - 128) * NCH + ch) * DIM) + c8;
  }

  f32x4 va[2][2], vb[2][2];
#pragma unroll
  for (int p = 0; p < 2; ++p) {
    va[p][0] = *reinterpret_cast<const f32x4*>(ap[p] + kbase);
    va[p][1] = *reinterpret_cast<const f32x4*>(ap[p] + kbase + 4);
    vb[p][0] = *reinterpret_cast<const f32x4*>(bp[p] + kbase);
    vb[p][1] = *reinterpret_cast<const f32x4*>(bp[p] + kbase + 4);
  }

  const int kend = kbase + kchunk;
  for (int k0 = kbase; k0 < kend; k0 += BK) {
    __syncthreads();  // previous iteration's ds_reads done
#pragma unroll
    for (int p = 0; p < 2; ++p) {
      u32x4 wa, wb;
      wa.x = pack_bf2(va[p][0].x, va[p][0].y);
      wa.y = pack_bf2(va[p][0].z, va[p][0].w);
      wa.z = pack_bf2(va[p][1].x, va[p][1].y);
      wa.w = pack_bf2(va[p][1].z, va[p][1].w);
      *reinterpret_cast<u32x4*>(&As[(r0 + p * 32) * LDSS + c8]) = wa;
      wb.x = pack_bf2(vb[p][0].x, vb[p][0].y);
      wb.y = pack_bf2(vb[p][0].z, vb[p][0].w);
      wb.z = pack_bf2(vb[p][1].x, vb[p][1].y);
      wb.w = pack_bf2(vb[p][1].z, vb[p][1].w);
      *reinterpret_cast<u32x4*>(&Bs[(r0 + p * 32) * LDSS + c8]) = wb;
    }
    // issue next K-step's loads NOW; they fly across the MFMA phase
    if (k0 + BK < kend) {
#pragma unroll
      for (int p = 0; p < 2; ++p) {
        va[p][0] = *reinterpret_cast<const f32x4*>(ap[p] + k0 + BK);
        va[p][1] = *reinterpret_cast<const f32x4*>(ap[p] + k0 + BK + 4);
        vb[p][0] = *reinterpret_cast<const f32x4*>(bp[p] + k0 + BK);
        vb[p][1] = *reinterpret_cast<const f32x4*>(bp[p] + k0 + BK + 4);
      }
    }
    // write-visibility barrier WITHOUT draining vmcnt (T4: never vmcnt(0) here)
    asm volatile("s_waitcnt lgkmcnt(0)" ::: "memory");
    __builtin_amdgcn_s_barrier();
    asm volatile("" ::: "memory");  // keep ds_reads below the barrier

#pragma unroll
    for (int kk = 0; kk < 2; ++kk) {
      const int kb = kk * 32 + (lane >> 4) * 8;
      bf16x8 a[2], b[2];
#pragma unroll
      for (int m = 0; m < 2; ++m)
        a[m] = *reinterpret_cast<const bf16x8*>(
            &As[(wrow + m * 16 + (lane & 15)) * LDSS + kb]);
#pragma unroll
      for (int n = 0; n < 2; ++n)
        b[n] = *reinterpret_cast<const bf16x8*>(
            &Bs[(wcol + n * 16 + (lane & 15)) * LDSS + kb]);
#pragma unroll
      for (int m = 0; m < 2; ++m)
#pragma unroll
        for (int n = 0; n < 2; ++n)
          acc[m][n] = __builtin_amdgcn_mfma_f32_16x16x32_bf16(a[m], b[n],
                                                              acc[m][n], 0, 0, 0);
    }
  }

  // C/D layout (m89): col = lane&15, row = (lane>>4)*4 + reg
  float* g = Gp + (size_t)(ch * (1 << kshift) + ks) * (NROW * NROW);
  const int rbase = ti * BM + wrow + ((lane >> 4) << 2);
  const int cbase = tj * BM + wcol + (lane & 15);
#pragma unroll
  for (int m = 0; m < 2; ++m)
#pragma unroll
    for (int n = 0; n < 2; ++n)
#pragma unroll
      for (int j = 0; j < 4; ++j)
        g[(size_t)(rbase + m * 16 + j) * NROW + (cbase + n * 16)] = acc[m][n][j];
}

// ---------------------------------------------------------------------------
// Gf = sum over K-split partials
__global__ __launch_bounds__(256) void fold_kernel(const f32x4* __restrict__ Gp,
                                                   f32x4* __restrict__ Gf, int P) {
  const int total = NCH * (NROW * NROW / 4);  // 344064 f32x4
  for (int idx = blockIdx.x * 256 + threadIdx.x; idx < total;
       idx += gridDim.x * 256) {
    const int ch = idx >> 14;       // 16384 f32x4 per channel
    const int off = idx & 16383;
    f32x4 s = Gp[(size_t)(ch * P) * 16384 + off];
    for (int p = 1; p < P; ++p) s += Gp[(size_t)(ch * P + p) * 16384 + off];
    Gf[idx] = s;
  }
}

// ---------------------------------------------------------------------------
__device__ __forceinline__ float block_sum256(float v, float* sm) {
#pragma unroll
  for (int o = 32; o > 0; o >>= 1) v += __shfl_down(v, o, 64);
  const int lane = threadIdx.x & 63;
  const int w = threadIdx.x >> 6;
  if (lane == 0) sm[w] = v;
  __syncthreads();
  float r = 0.f;
  if (threadIdx.x == 0) r = sm[0] + sm[1] + sm[2] + sm[3];
  __syncthreads();
  return r;  // valid on thread 0
}

// per (ch, quarter): partial sum(G) and partial trace(G)
__global__ __launch_bounds__(256) void bw_part_kernel(const float* __restrict__ Gf,
                                                      float* __restrict__ sums) {
  const int ch = blockIdx.y;
  const int part = blockIdx.x;  // 0..3
  const float* g = Gf + (size_t)ch * (NROW * NROW);
  const f32x4* gv = reinterpret_cast<const f32x4*>(g + part * 16384);
  float s = 0.f;
  for (int i = threadIdx.x; i < 4096; i += 256) {
    f32x4 v = gv[i];
    s += (v.x + v.y) + (v.z + v.w);
  }
  float tr = (threadIdx.x < 64) ? g[(part * 64 + threadIdx.x) * (NROW + 1)] : 0.f;
  __shared__ float sm[4];
  float sG = block_sum256(s, sm);
  float sT = block_sum256(tr, sm);
  if (threadIdx.x == 0) {
    sums[ch * 8 + part] = sG;
    sums[ch * 8 + 4 + part] = sT;
  }
}

// per (ch, 32-row slab): sum_ij s_i s_j sum_a exp(-L2_ij/(bw*2^a))
__global__ __launch_bounds__(256) void mmd_kernel(const float* __restrict__ Gf,
                                                  const float* __restrict__ sums,
                                                  float* __restrict__ partial) {
  const int ch = blockIdx.y;
  const int part = blockIdx.x;  // 0..7
  const int tid = threadIdx.x;
  const float* g = Gf + (size_t)ch * (NROW * NROW);
  // reconstruct bandwidth from the 8 per-channel scalars (all threads, broadcast)
  const float* sc = sums + ch * 8;
  float sumG = (sc[0] + sc[1]) + (sc[2] + sc[3]);
  float tr = (sc[4] + sc[5]) + (sc[6] + sc[7]);
  float sumL2 = 2.f * NROW * tr - 2.f * sumG;
  float bw = sumL2 / (float)(NROW * NROW - NROW) * 0.25f;

  __shared__ float diag[NROW];
  diag[tid] = g[tid * (NROW + 1)];
  __syncthreads();
  float inv[5];
#pragma unroll
  for (int a = 0; a < 5; ++a) inv[a] = -1.f / (bw * (float)(1 << a));
  const float dj = diag[tid];
  float acc = 0.f;
#pragma unroll 4
  for (int it = 0; it < 32; ++it) {
    const int i = part * 32 + it;
    const float L2 = diag[i] + dj - 2.f * g[i * NROW + tid];
    float kv = 0.f;
#pragma unroll
    for (int a = 0; a < 5; ++a) kv += __expf(L2 * inv[a]);
    acc += ((i ^ tid) & 128) ? -kv : kv;
  }
  __shared__ float sm[4];
  float tot = block_sum256(acc, sm);
  if (tid == 0) partial[ch * 8 + part] = tot;
}

__global__ __launch_bounds__(256) void final_kernel(const float* __restrict__ partial,
                                                    float* __restrict__ out) {
  const int tid = threadIdx.x;
  float v = (tid < NCH * 8) ? partial[tid] : 0.f;
  __shared__ float sm[4];
  float tot = block_sum256(v, sm);
  if (tid == 0) out[0] = tot * (1.f / (NCH * 128.f * 128.f));
}

// ---------------------------------------------------------------------------
extern "C" void kernel_launch(void* const* d_in, const int* in_sizes, int n_in,
                              void* d_out, int out_size, void* d_ws, size_t ws_size,
                              hipStream_t stream) {
  const float* src = (const float*)d_in[0];
  const float* tgt = (const float*)d_in[1];
  float* out = (float*)d_out;
  const size_t GSZ = (size_t)NROW * NROW;  // 65536

  // pick K-split by available workspace: P slices + 1 folded + scalars.
  // P=8 -> 2688 blocks = 10.5 blocks/CU demanded vs 8 resident (LDS cap):
  // steady-state occupancy pinned at the cap, launch/drain tail amortized.
  int kshift = 0;
  if (ws_size >= (NCH * 9 * GSZ + 64) * sizeof(float)) kshift = 3;
  else if (ws_size >= (NCH * 5 * GSZ + 64) * sizeof(float)) kshift = 2;
  else if (ws_size >= (NCH * 3 * GSZ + 64) * sizeof(float)) kshift = 1;
  const int P = 1 << kshift;

  float* Gp = (float*)d_ws;
  float* Gf = (P > 1) ? Gp + (size_t)NCH * P * GSZ : Gp;  // P==1: alias, skip fold
  float* sums = Gf + (size_t)NCH * GSZ;
  float* partial = sums + NCH * 8;

  gram_kernel<<<dim3(4, 4, NCH * P), 256, 0, stream>>>(src, tgt, Gp, kshift,
                                                       DIM >> kshift);
  if (P > 1)
    fold_kernel<<<dim3(1344), 256, 0, stream>>>((const f32x4*)Gp, (f32x4*)Gf, P);
  bw_part_kernel<<<dim3(4, NCH), 256, 0, stream>>>(Gf, sums);
  mmd_kernel<<<dim3(8, NCH), 256, 0, stream>>>(Gf, sums, partial);
  final_kernel<<<1, 256, 0, stream>>>(partial, out);
}

// Round 7
// 74.213 us; speedup vs baseline: 1.4145x; 1.4145x over previous
//
#include <hip/hip_runtime.h>
#include <hip/hip_bf16.h>
#include <stdint.h>

typedef __attribute__((ext_vector_type(4))) float f32x4;
typedef __attribute__((ext_vector_type(8))) short bf16x8;
typedef __attribute__((ext_vector_type(4))) uint32_t u32x4;

#define NCH 21
#define NROW 256
#define DIM 4096
#define BM 64
#define BK 64
#define LDSS 72   // row stride in ushorts: 144 B
#define NTILE 10  // upper-triangle 64x64 tile pairs of the 256x256 Gram

__device__ const int g_TI[NTILE] = {0, 0, 0, 0, 1, 1, 1, 2, 2, 3};
__device__ const int g_TJ[NTILE] = {0, 1, 2, 3, 1, 2, 3, 2, 3, 3};

__device__ __forceinline__ uint32_t pack_bf2(float x, float y) {
  __hip_bfloat162 h = __float22bfloat162_rn(float2{x, y});  // v_cvt_pk_bf16_f32
  union { __hip_bfloat162 h; uint32_t u; } c;
  c.h = h;
  return c.u;
}

// ---------------------------------------------------------------------------
// Upper-triangle partial Gram. Diagonal tile-pairs stage only As (B := A).
// Single LDS buffer, prefetch-into-regs across a lgkmcnt-only s_barrier.
// ---------------------------------------------------------------------------
__global__ __launch_bounds__(256) void gram_kernel(
    const float* __restrict__ src, const float* __restrict__ tgt,
    float* __restrict__ Gp, int kshift, int kchunk) {
  const int bz = blockIdx.y;
  const int ch = bz >> kshift;
  const int ks = bz & ((1 << kshift) - 1);
  const int kbase = ks * kchunk;
  const int ti = g_TI[blockIdx.x];
  const int tj = g_TJ[blockIdx.x];
  const bool isdiag = (ti == tj);
  const int tid = threadIdx.x;
  const int lane = tid & 63;

  __shared__ __attribute__((aligned(16))) ushort As[BM * LDSS];
  __shared__ __attribute__((aligned(16))) ushort Bs[BM * LDSS];

  f32x4 acc[2][2];
#pragma unroll
  for (int m = 0; m < 2; ++m)
#pragma unroll
    for (int n = 0; n < 2; ++n)
      acc[m][n] = (f32x4){0.f, 0.f, 0.f, 0.f};

  const int wave = tid >> 6;
  const int wrow = (wave >> 1) * 32;
  const int wcol = (wave & 1) * 32;

  // staging geometry: rows r0 and r0+32, 8 floats starting at column c8
  const int r0 = tid >> 3;          // 0..31
  const int c8 = (tid & 7) * 8;     // 0,8,...,56
  const float* ap[2];
  const float* bp[2];
#pragma unroll
  for (int p = 0; p < 2; ++p) {
    int ra = ti * BM + r0 + p * 32;
    int rb = tj * BM + r0 + p * 32;
    ap[p] = ((ra < 128) ? src + ((size_t)ra * NCH + ch) * DIM
                        : tgt + ((size_t)(ra - 128) * NCH + ch) * DIM) + c8;
    bp[p] = ((rb < 128) ? src + ((size_t)rb * NCH + ch) * DIM
                        : tgt + ((size_t)(rb - 128) * NCH + ch) * DIM) + c8;
  }

  f32x4 va[2][2], vb[2][2];
#pragma unroll
  for (int p = 0; p < 2; ++p) {
    va[p][0] = *reinterpret_cast<const f32x4*>(ap[p] + kbase);
    va[p][1] = *reinterpret_cast<const f32x4*>(ap[p] + kbase + 4);
    if (!isdiag) {
      vb[p][0] = *reinterpret_cast<const f32x4*>(bp[p] + kbase);
      vb[p][1] = *reinterpret_cast<const f32x4*>(bp[p] + kbase + 4);
    }
  }

  const int kend = kbase + kchunk;
  for (int k0 = kbase; k0 < kend; k0 += BK) {
    __syncthreads();  // previous iteration's ds_reads done
#pragma unroll
    for (int p = 0; p < 2; ++p) {
      u32x4 wa;
      wa.x = pack_bf2(va[p][0].x, va[p][0].y);
      wa.y = pack_bf2(va[p][0].z, va[p][0].w);
      wa.z = pack_bf2(va[p][1].x, va[p][1].y);
      wa.w = pack_bf2(va[p][1].z, va[p][1].w);
      *reinterpret_cast<u32x4*>(&As[(r0 + p * 32) * LDSS + c8]) = wa;
      if (!isdiag) {
        u32x4 wb;
        wb.x = pack_bf2(vb[p][0].x, vb[p][0].y);
        wb.y = pack_bf2(vb[p][0].z, vb[p][0].w);
        wb.z = pack_bf2(vb[p][1].x, vb[p][1].y);
        wb.w = pack_bf2(vb[p][1].z, vb[p][1].w);
        *reinterpret_cast<u32x4*>(&Bs[(r0 + p * 32) * LDSS + c8]) = wb;
      }
    }
    // issue next K-step's loads NOW; they fly across the MFMA phase
    if (k0 + BK < kend) {
#pragma unroll
      for (int p = 0; p < 2; ++p) {
        va[p][0] = *reinterpret_cast<const f32x4*>(ap[p] + k0 + BK);
        va[p][1] = *reinterpret_cast<const f32x4*>(ap[p] + k0 + BK + 4);
        if (!isdiag) {
          vb[p][0] = *reinterpret_cast<const f32x4*>(bp[p] + k0 + BK);
          vb[p][1] = *reinterpret_cast<const f32x4*>(bp[p] + k0 + BK + 4);
        }
      }
    }
    // write-visibility barrier WITHOUT draining vmcnt
    asm volatile("s_waitcnt lgkmcnt(0)" ::: "memory");
    __builtin_amdgcn_s_barrier();
    asm volatile("" ::: "memory");

    const ushort* Bsrc = isdiag ? As : Bs;
#pragma unroll
    for (int kk = 0; kk < 2; ++kk) {
      const int kb = kk * 32 + (lane >> 4) * 8;
      bf16x8 a[2], b[2];
#pragma unroll
      for (int m = 0; m < 2; ++m)
        a[m] = *reinterpret_cast<const bf16x8*>(
            &As[(wrow + m * 16 + (lane & 15)) * LDSS + kb]);
#pragma unroll
      for (int n = 0; n < 2; ++n)
        b[n] = *reinterpret_cast<const bf16x8*>(
            &Bsrc[(wcol + n * 16 + (lane & 15)) * LDSS + kb]);
#pragma unroll
      for (int m = 0; m < 2; ++m)
#pragma unroll
        for (int n = 0; n < 2; ++n)
          acc[m][n] = __builtin_amdgcn_mfma_f32_16x16x32_bf16(a[m], b[n],
                                                              acc[m][n], 0, 0, 0);
    }
  }

  // C/D layout (m89): col = lane&15, row = (lane>>4)*4 + reg
  float* g = Gp + (size_t)(ch * (1 << kshift) + ks) * (NROW * NROW);
  const int rbase = ti * BM + wrow + ((lane >> 4) << 2);
  const int cbase = tj * BM + wcol + (lane & 15);
#pragma unroll
  for (int m = 0; m < 2; ++m)
#pragma unroll
    for (int n = 0; n < 2; ++n)
#pragma unroll
      for (int j = 0; j < 4; ++j)
        g[(size_t)(rbase + m * 16 + j) * NROW + (cbase + n * 16)] = acc[m][n][j];
}

// ---------------------------------------------------------------------------
// Gf = sum over K-split partials; upper-triangle tiles only.
// One element per thread: NCH*10*1024 f32x4 = 215040 -> 840 blocks of 256.
__global__ __launch_bounds__(256) void fold_kernel(const f32x4* __restrict__ Gp,
                                                   f32x4* __restrict__ Gf, int P) {
  const int idx = blockIdx.x * 256 + threadIdx.x;
  const int ch = idx / (NTILE * 1024);
  const int rem = idx - ch * (NTILE * 1024);
  const int t = rem >> 10;
  const int off = rem & 1023;
  const int r = off >> 4;       // 0..63
  const int c4 = off & 15;      // 0..15
  const int base_v = (g_TI[t] * 64 + r) * 64 + g_TJ[t] * 16 + c4;
  f32x4 s = Gp[(size_t)(ch * P) * 16384 + base_v];
  for (int p = 1; p < P; ++p) s += Gp[(size_t)(ch * P + p) * 16384 + base_v];
  Gf[(size_t)ch * 16384 + base_v] = s;
}

// ---------------------------------------------------------------------------
__device__ __forceinline__ float block_sum256(float v, float* sm) {
#pragma unroll
  for (int o = 32; o > 0; o >>= 1) v += __shfl_down(v, o, 64);
  const int lane = threadIdx.x & 63;
  const int w = threadIdx.x >> 6;
  if (lane == 0) sm[w] = v;
  __syncthreads();
  float r = 0.f;
  if (threadIdx.x == 0) r = sm[0] + sm[1] + sm[2] + sm[3];
  __syncthreads();
  return r;  // valid on thread 0
}

// per (tile, ch): tile sum -> sums[ch*20+t]; diag tiles also local trace
// -> sums[ch*20+10+ti]. Layout: 20 floats per channel.
__global__ __launch_bounds__(256) void tile_sum_kernel(const float* __restrict__ Gf,
                                                       float* __restrict__ sums) {
  const int t = blockIdx.x;
  const int ch = blockIdx.y;
  const int ti = g_TI[t], tj = g_TJ[t];
  const float* g = Gf + (size_t)ch * (NROW * NROW);
  const int tid = threadIdx.x;
  const int col = tid & 63;
  const int q = tid >> 6;
  float s = 0.f, tr = 0.f;
#pragma unroll
  for (int it = 0; it < 16; ++it) {
    const int r = it * 4 + q;
    const float v = g[(size_t)(ti * 64 + r) * NROW + tj * 64 + col];
    s += v;
    if (ti == tj && r == col) tr += v;
  }
  __shared__ float sm[4];
  float sG = block_sum256(s, sm);
  float sT = block_sum256(tr, sm);
  if (tid == 0) {
    sums[ch * 20 + t] = sG;
    if (ti == tj) sums[ch * 20 + 10 + ti] = sT;
  }
}

// per (tile, ch): w * sign * sum over tile of sum_a exp(-L2/(bw*2^a)).
// Sign is tile-uniform (bit7 of row/col index is tile-determined).
__global__ __launch_bounds__(256) void mmd_kernel(const float* __restrict__ Gf,
                                                  const float* __restrict__ sums,
                                                  float* __restrict__ partial) {
  const int t = blockIdx.x;
  const int ch = blockIdx.y;
  const int ti = g_TI[t], tj = g_TJ[t];
  const int tid = threadIdx.x;
  const float* g = Gf + (size_t)ch * (NROW * NROW);

  // reconstruct bandwidth: sum(G) = sum_diag + 2*sum_offdiag; trace from diag tiles
  const float* sc = sums + ch * 20;
  float sumG = 0.f;
#pragma unroll
  for (int k = 0; k < NTILE; ++k)
    sumG += (g_TI[k] == g_TJ[k] ? 1.f : 2.f) * sc[k];
  const float trace = (sc[10] + sc[11]) + (sc[12] + sc[13]);
  const float sumL2 = 2.f * NROW * trace - 2.f * sumG;
  const float bw = sumL2 / (float)(NROW * NROW - NROW) * 0.25f;
  float inv[5];
#pragma unroll
  for (int a = 0; a < 5; ++a) inv[a] = -1.f / (bw * (float)(1 << a));

  __shared__ float dA[64], dB[64];
  if (tid < 64) dA[tid] = g[(size_t)(ti * 64 + tid) * (NROW + 1)];
  else if (tid < 128) dB[tid - 64] = g[(size_t)(tj * 64 + (tid - 64)) * (NROW + 1)];
  __syncthreads();

  const int col = tid & 63;
  const int q = tid >> 6;
  const float dj = dB[col];
  float acc = 0.f;
#pragma unroll 4
  for (int it = 0; it < 16; ++it) {
    const int r = it * 4 + q;
    const float L2 = dA[r] + dj - 2.f * g[(size_t)(ti * 64 + r) * NROW + tj * 64 + col];
    float kv = 0.f;
#pragma unroll
    for (int a = 0; a < 5; ++a) kv += __expf(L2 * inv[a]);
    acc += kv;
  }
  __shared__ float sm[4];
  float tot = block_sum256(acc, sm);
  if (tid == 0) {
    float w = (ti == tj) ? 1.f : 2.f;                    // off-diag mirror
    float sgn = ((ti >= 2) == (tj >= 2)) ? 1.f : -1.f;   // XX/YY + , XY/YX -
    partial[ch * NTILE + t] = tot * w * sgn;
  }
}

__global__ __launch_bounds__(256) void final_kernel(const float* __restrict__ partial,
                                                    float* __restrict__ out) {
  const int tid = threadIdx.x;
  float v = (tid < NCH * NTILE) ? partial[tid] : 0.f;
  __shared__ float sm[4];
  float tot = block_sum256(v, sm);
  if (tid == 0) out[0] = tot * (1.f / (NCH * 128.f * 128.f));
}

// ---------------------------------------------------------------------------
extern "C" void kernel_launch(void* const* d_in, const int* in_sizes, int n_in,
                              void* d_out, int out_size, void* d_ws, size_t ws_size,
                              hipStream_t stream) {
  const float* src = (const float*)d_in[0];
  const float* tgt = (const float*)d_in[1];
  float* out = (float*)d_out;
  const size_t GSZ = (size_t)NROW * NROW;  // 65536

  int kshift = 0;
  if (ws_size >= (NCH * 9 * GSZ + 512) * sizeof(float)) kshift = 3;
  else if (ws_size >= (NCH * 5 * GSZ + 512) * sizeof(float)) kshift = 2;
  else if (ws_size >= (NCH * 3 * GSZ + 512) * sizeof(float)) kshift = 1;
  const int P = 1 << kshift;

  float* Gp = (float*)d_ws;
  float* Gf = (P > 1) ? Gp + (size_t)NCH * P * GSZ : Gp;  // P==1: alias, skip fold
  float* sums = Gf + (size_t)NCH * GSZ;                   // NCH*20
  float* partial = sums + NCH * 20;                       // NCH*10

  gram_kernel<<<dim3(NTILE, NCH * P), 256, 0, stream>>>(src, tgt, Gp, kshift,
                                                        DIM >> kshift);
  if (P > 1)
    fold_kernel<<<dim3(NCH * NTILE * 4), 256, 0, stream>>>((const f32x4*)Gp,
                                                           (f32x4*)Gf, P);
  tile_sum_kernel<<<dim3(NTILE, NCH), 256, 0, stream>>>(Gf, sums);
  mmd_kernel<<<dim3(NTILE, NCH), 256, 0, stream>>>(Gf, sums, partial);
  final_kernel<<<1, 256, 0, stream>>>(partial, out);
}

// Round 8
// 47.416 us; speedup vs baseline: 2.2140x; 1.5652x over previous
//
#include <hip/hip_runtime.h>
#include <hip/hip_bf16.h>
#include <stdint.h>

typedef __attribute__((ext_vector_type(4))) float f32x4;
typedef __attribute__((ext_vector_type(8))) short bf16x8;
typedef __attribute__((ext_vector_type(4))) uint32_t u32x4;

#define NCH 21
#define NROW 256
#define DIM 4096
#define BM 64
#define BK 64
#define LDSS 72   // row stride in ushorts: 144 B
#define NTILE 10  // upper-triangle 64x64 tile pairs of the 256x256 Gram

__device__ const int g_TI[NTILE] = {0, 0, 0, 0, 1, 1, 1, 2, 2, 3};
__device__ const int g_TJ[NTILE] = {0, 1, 2, 3, 1, 2, 3, 2, 3, 3};

__device__ __forceinline__ uint32_t pack_bf2(float x, float y) {
  __hip_bfloat162 h = __float22bfloat162_rn(float2{x, y});  // v_cvt_pk_bf16_f32
  union { __hip_bfloat162 h; uint32_t u; } c;
  c.h = h;
  return c.u;
}

// ---------------------------------------------------------------------------
// Upper-triangle partial Gram, XCD-grouped: all 10 tiles of one (ch,ks)
// group land on ONE XCD (bijective m204 mapping) so the 4 unique 64-row
// panels are fetched from HBM once per group and re-staged from XCD-L2.
// Diagonal tile-pairs stage only As (B := A). Single LDS buffer,
// register prefetch across a lgkmcnt-only s_barrier (never vmcnt(0)).
// ---------------------------------------------------------------------------
__global__ __launch_bounds__(256) void gram_kernel(
    const float* __restrict__ src, const float* __restrict__ tgt,
    float* __restrict__ Gp, int kshift, int kchunk) {
  const int P = 1 << kshift;
  const int NG = NCH << kshift;          // number of (ch,ks) groups
  const int q = NG >> 3, r8 = NG & 7;    // groups per XCD (bijective split)
  const int x = blockIdx.x & 7;          // XCD id (empirical round-robin)
  const int slot = blockIdx.x >> 3;
  const int cnt = q + (x < r8 ? 1 : 0);
  if (slot >= cnt * NTILE) return;       // padded grid tail (uniform exit)
  const int gbase = (x < r8) ? x * (q + 1) : r8 * (q + 1) + (x - r8) * q;
  const int gi = slot / NTILE;
  const int t = slot - gi * NTILE;
  const int g = gbase + gi;
  const int ch = g >> kshift;
  const int ks = g & (P - 1);
  const int kbase = ks * kchunk;
  const int ti = g_TI[t];
  const int tj = g_TJ[t];
  const bool isdiag = (ti == tj);
  const int tid = threadIdx.x;
  const int lane = tid & 63;

  __shared__ __attribute__((aligned(16))) ushort As[BM * LDSS];
  __shared__ __attribute__((aligned(16))) ushort Bs[BM * LDSS];

  f32x4 acc[2][2];
#pragma unroll
  for (int m = 0; m < 2; ++m)
#pragma unroll
    for (int n = 0; n < 2; ++n)
      acc[m][n] = (f32x4){0.f, 0.f, 0.f, 0.f};

  const int wave = tid >> 6;
  const int wrow = (wave >> 1) * 32;
  const int wcol = (wave & 1) * 32;

  // staging geometry: rows r0 and r0+32, 8 floats starting at column c8
  const int r0 = tid >> 3;          // 0..31
  const int c8 = (tid & 7) * 8;     // 0,8,...,56
  const float* ap[2];
  const float* bp[2];
#pragma unroll
  for (int p = 0; p < 2; ++p) {
    int ra = ti * BM + r0 + p * 32;
    int rb = tj * BM + r0 + p * 32;
    ap[p] = ((ra < 128) ? src + ((size_t)ra * NCH + ch) * DIM
                        : tgt + ((size_t)(ra - 128) * NCH + ch) * DIM) + c8;
    bp[p] = ((rb < 128) ? src + ((size_t)rb * NCH + ch) * DIM
                        : tgt + ((size_t)(rb - 128) * NCH + ch) * DIM) + c8;
  }

  f32x4 va[2][2], vb[2][2];
#pragma unroll
  for (int p = 0; p < 2; ++p) {
    va[p][0] = *reinterpret_cast<const f32x4*>(ap[p] + kbase);
    va[p][1] = *reinterpret_cast<const f32x4*>(ap[p] + kbase + 4);
    if (!isdiag) {
      vb[p][0] = *reinterpret_cast<const f32x4*>(bp[p] + kbase);
      vb[p][1] = *reinterpret_cast<const f32x4*>(bp[p] + kbase + 4);
    }
  }

  const int kend = kbase + kchunk;
  for (int k0 = kbase; k0 < kend; k0 += BK) {
    __syncthreads();  // previous iteration's ds_reads done
#pragma unroll
    for (int p = 0; p < 2; ++p) {
      u32x4 wa;
      wa.x = pack_bf2(va[p][0].x, va[p][0].y);
      wa.y = pack_bf2(va[p][0].z, va[p][0].w);
      wa.z = pack_bf2(va[p][1].x, va[p][1].y);
      wa.w = pack_bf2(va[p][1].z, va[p][1].w);
      *reinterpret_cast<u32x4*>(&As[(r0 + p * 32) * LDSS + c8]) = wa;
      if (!isdiag) {
        u32x4 wb;
        wb.x = pack_bf2(vb[p][0].x, vb[p][0].y);
        wb.y = pack_bf2(vb[p][0].z, vb[p][0].w);
        wb.z = pack_bf2(vb[p][1].x, vb[p][1].y);
        wb.w = pack_bf2(vb[p][1].z, vb[p][1].w);
        *reinterpret_cast<u32x4*>(&Bs[(r0 + p * 32) * LDSS + c8]) = wb;
      }
    }
    // issue next K-step's loads NOW; they fly across the MFMA phase
    if (k0 + BK < kend) {
#pragma unroll
      for (int p = 0; p < 2; ++p) {
        va[p][0] = *reinterpret_cast<const f32x4*>(ap[p] + k0 + BK);
        va[p][1] = *reinterpret_cast<const f32x4*>(ap[p] + k0 + BK + 4);
        if (!isdiag) {
          vb[p][0] = *reinterpret_cast<const f32x4*>(bp[p] + k0 + BK);
          vb[p][1] = *reinterpret_cast<const f32x4*>(bp[p] + k0 + BK + 4);
        }
      }
    }
    // write-visibility barrier WITHOUT draining vmcnt
    asm volatile("s_waitcnt lgkmcnt(0)" ::: "memory");
    __builtin_amdgcn_s_barrier();
    asm volatile("" ::: "memory");

    const ushort* Bsrc = isdiag ? As : Bs;
#pragma unroll
    for (int kk = 0; kk < 2; ++kk) {
      const int kb = kk * 32 + (lane >> 4) * 8;
      bf16x8 a[2], b[2];
#pragma unroll
      for (int m = 0; m < 2; ++m)
        a[m] = *reinterpret_cast<const bf16x8*>(
            &As[(wrow + m * 16 + (lane & 15)) * LDSS + kb]);
#pragma unroll
      for (int n = 0; n < 2; ++n)
        b[n] = *reinterpret_cast<const bf16x8*>(
            &Bsrc[(wcol + n * 16 + (lane & 15)) * LDSS + kb]);
#pragma unroll
      for (int m = 0; m < 2; ++m)
#pragma unroll
        for (int n = 0; n < 2; ++n)
          acc[m][n] = __builtin_amdgcn_mfma_f32_16x16x32_bf16(a[m], b[n],
                                                              acc[m][n], 0, 0, 0);
    }
  }

  // C/D layout (m89): col = lane&15, row = (lane>>4)*4 + reg
  float* gp = Gp + (size_t)(ch * P + ks) * (NROW * NROW);
  const int rbase = ti * BM + wrow + ((lane >> 4) << 2);
  const int cbase = tj * BM + wcol + (lane & 15);
#pragma unroll
  for (int m = 0; m < 2; ++m)
#pragma unroll
    for (int n = 0; n < 2; ++n)
#pragma unroll
      for (int j = 0; j < 4; ++j)
        gp[(size_t)(rbase + m * 16 + j) * NROW + (cbase + n * 16)] = acc[m][n][j];
}

// ---------------------------------------------------------------------------
__device__ __forceinline__ float block_sum256(float v, float* sm) {
#pragma unroll
  for (int o = 32; o > 0; o >>= 1) v += __shfl_down(v, o, 64);
  const int lane = threadIdx.x & 63;
  const int w = threadIdx.x >> 6;
  if (lane == 0) sm[w] = v;
  __syncthreads();
  float r = 0.f;
  if (threadIdx.x == 0) r = sm[0] + sm[1] + sm[2] + sm[3];
  __syncthreads();
  return r;  // valid on thread 0
}

// ---------------------------------------------------------------------------
// Fold K-split partials for one (ch,tile) AND produce tile sum + diag trace.
// sums layout: 20 floats/ch: [0..9] tile sums, [10..13] diag-tile traces.
__global__ __launch_bounds__(256) void foldsum_kernel(
    const f32x4* __restrict__ Gp, f32x4* __restrict__ Gf,
    float* __restrict__ sums, int P) {
  const int t = blockIdx.x;
  const int ch = blockIdx.y;
  const int ti = g_TI[t], tj = g_TJ[t];
  const bool isdiag = (ti == tj);
  const int tid = threadIdx.x;
  float s = 0.f, tr = 0.f;
#pragma unroll
  for (int i = 0; i < 4; ++i) {
    const int idx4 = tid * 4 + i;
    const int rrow = idx4 >> 4;       // 0..63
    const int c4 = idx4 & 15;         // 0..15
    const int base_v = (ti * 64 + rrow) * 64 + tj * 16 + c4;
    f32x4 v = Gp[(size_t)(ch * P) * 16384 + base_v];
    for (int p = 1; p < P; ++p) v += Gp[(size_t)(ch * P + p) * 16384 + base_v];
    Gf[(size_t)ch * 16384 + base_v] = v;
    s += (v.x + v.y) + (v.z + v.w);
    if (isdiag) {
      const int cb = c4 * 4;
#pragma unroll
      for (int e = 0; e < 4; ++e)
        if (cb + e == rrow) tr += v[e];
    }
  }
  __shared__ float sm[4];
  float sG = block_sum256(s, sm);
  float sT = block_sum256(tr, sm);
  if (tid == 0) {
    sums[ch * 20 + t] = sG;
    if (isdiag) sums[ch * 20 + 10 + ti] = sT;
  }
}

// ---------------------------------------------------------------------------
// per (tile, ch): w * sign * sum over tile of sum_a exp(-L2/(bw*2^a)).
__global__ __launch_bounds__(256) void mmd_kernel(const float* __restrict__ Gf,
                                                  const float* __restrict__ sums,
                                                  float* __restrict__ partial) {
  const int t = blockIdx.x;
  const int ch = blockIdx.y;
  const int ti = g_TI[t], tj = g_TJ[t];
  const int tid = threadIdx.x;
  const float* g = Gf + (size_t)ch * (NROW * NROW);

  // bandwidth: sum(G) = sum_diag_tiles + 2*sum_offdiag_tiles
  const float* sc = sums + ch * 20;
  float sumG = 0.f;
#pragma unroll
  for (int k = 0; k < NTILE; ++k)
    sumG += (g_TI[k] == g_TJ[k] ? 1.f : 2.f) * sc[k];
  const float trace = (sc[10] + sc[11]) + (sc[12] + sc[13]);
  const float sumL2 = 2.f * NROW * trace - 2.f * sumG;
  const float bw = sumL2 / (float)(NROW * NROW - NROW) * 0.25f;
  float inv[5];
#pragma unroll
  for (int a = 0; a < 5; ++a) inv[a] = -1.f / (bw * (float)(1 << a));

  __shared__ float dA[64], dB[64];
  if (tid < 64) dA[tid] = g[(size_t)(ti * 64 + tid) * (NROW + 1)];
  else if (tid < 128) dB[tid - 64] = g[(size_t)(tj * 64 + (tid - 64)) * (NROW + 1)];
  __syncthreads();

  const int col = tid & 63;
  const int qq = tid >> 6;
  const float dj = dB[col];
  float acc = 0.f;
#pragma unroll 4
  for (int it = 0; it < 16; ++it) {
    const int r = it * 4 + qq;
    const float L2 = dA[r] + dj - 2.f * g[(size_t)(ti * 64 + r) * NROW + tj * 64 + col];
    float kv = 0.f;
#pragma unroll
    for (int a = 0; a < 5; ++a) kv += __expf(L2 * inv[a]);
    acc += kv;
  }
  __shared__ float sm[4];
  float tot = block_sum256(acc, sm);
  if (tid == 0) {
    float w = (ti == tj) ? 1.f : 2.f;                    // off-diag mirror
    float sgn = ((ti >= 2) == (tj >= 2)) ? 1.f : -1.f;   // XX/YY + , XY/YX -
    partial[ch * NTILE + t] = tot * w * sgn;
  }
}

__global__ __launch_bounds__(256) void final_kernel(const float* __restrict__ partial,
                                                    float* __restrict__ out) {
  const int tid = threadIdx.x;
  float v = (tid < NCH * NTILE) ? partial[tid] : 0.f;
  __shared__ float sm[4];
  float tot = block_sum256(v, sm);
  if (tid == 0) out[0] = tot * (1.f / (NCH * 128.f * 128.f));
}

// ---------------------------------------------------------------------------
extern "C" void kernel_launch(void* const* d_in, const int* in_sizes, int n_in,
                              void* d_out, int out_size, void* d_ws, size_t ws_size,
                              hipStream_t stream) {
  const float* src = (const float*)d_in[0];
  const float* tgt = (const float*)d_in[1];
  float* out = (float*)d_out;
  const size_t GSZ = (size_t)NROW * NROW;  // 65536

  int kshift = 0;
  if (ws_size >= (NCH * 9 * GSZ + 512) * sizeof(float)) kshift = 3;
  else if (ws_size >= (NCH * 5 * GSZ + 512) * sizeof(float)) kshift = 2;
  else if (ws_size >= (NCH * 3 * GSZ + 512) * sizeof(float)) kshift = 1;
  const int P = 1 << kshift;

  float* Gp = (float*)d_ws;
  float* Gf = (P > 1) ? Gp + (size_t)NCH * P * GSZ : Gp;  // P==1: alias, fold is copy
  float* sums = Gf + (size_t)NCH * GSZ;                   // NCH*20
  float* partial = sums + NCH * 20;                       // NCH*10

  // XCD-grouped grid: 8 * max-slots-per-XCD (bijective m204 split; in-kernel guard)
  const int NG = NCH * P;
  const int q = NG / 8, r8 = NG % 8;
  const int grid = 8 * (q + (r8 ? 1 : 0)) * NTILE;

  gram_kernel<<<dim3(grid), 256, 0, stream>>>(src, tgt, Gp, kshift, DIM >> kshift);
  foldsum_kernel<<<dim3(NTILE, NCH), 256, 0, stream>>>((const f32x4*)Gp,
                                                       (f32x4*)Gf, sums, P);
  mmd_kernel<<<dim3(NTILE, NCH), 256, 0, stream>>>(Gf, sums, partial);
  final_kernel<<<1, 256, 0, stream>>>(partial, out);
}

// Round 9
// 45.914 us; speedup vs baseline: 2.2864x; 1.0327x over previous
//
#include <hip/hip_runtime.h>
#include <hip/hip_bf16.h>
#include <stdint.h>

typedef __attribute__((ext_vector_type(4))) float f32x4;
typedef __attribute__((ext_vector_type(8))) short bf16x8;
typedef __attribute__((ext_vector_type(4))) uint32_t u32x4;

#define NCH 21
#define NROW 256
#define DIM 4096
#define BMP 128   // pair-merged tile dim
#define BK 64
#define LDSS 72   // row stride in ushorts: 144 B
#define NTILE 10  // upper-triangle 64x64 tiles of the 256x256 Gram

__device__ const int g_TI[NTILE] = {0, 0, 0, 0, 1, 1, 1, 2, 2, 3};
__device__ const int g_TJ[NTILE] = {0, 1, 2, 3, 1, 2, 3, 2, 3, 3};

__device__ __forceinline__ uint32_t pack_bf2(float x, float y) {
  __hip_bfloat162 h = __float22bfloat162_rn(float2{x, y});  // v_cvt_pk_bf16_f32
  union { __hip_bfloat162 h; uint32_t u; } c;
  c.h = h;
  return c.u;
}

// ---------------------------------------------------------------------------
// Pair-merged partial Gram: per (ch,ks) group, 3 blocks of 512 threads:
//   bt=0: rows(0,1) x cols(0,1)  -- diagonal pair, stages ONE 128-row panel
//   bt=1: rows(2,3) x cols(2,3)  -- diagonal pair
//   bt=2: rows(0,1) x cols(2,3)  -- off-diagonal, stages two panels
// Panel-stagings per group: 8 (vs 16 for 64x64 tiling) -> staging instr
// stream halved. Mirror subtiles (1,0)/(3,2) computed but not written, so
// Gp holds exactly the 10 upper-tri tiles (bit-identical to R8).
// XCD-grouped (bijective m204 split): a group's 3 blocks share one XCD-L2.
// Single LDS buffer, register prefetch across a lgkmcnt-only s_barrier.
// ---------------------------------------------------------------------------
__global__ __launch_bounds__(512) void gram_kernel(
    const float* __restrict__ src, const float* __restrict__ tgt,
    float* __restrict__ Gp, int kshift, int kchunk) {
  const int P = 1 << kshift;
  const int NG = NCH << kshift;          // number of (ch,ks) groups
  const int q = NG >> 3, r8 = NG & 7;    // groups per XCD
  const int x = blockIdx.x & 7;          // XCD id (empirical round-robin)
  const int slot = blockIdx.x >> 3;
  const int cnt = q + (x < r8 ? 1 : 0);
  if (slot >= cnt * 3) return;           // padded grid tail (uniform exit)
  const int gbase = (x < r8) ? x * (q + 1) : r8 * (q + 1) + (x - r8) * q;
  const int gi = slot / 3;
  const int bt = slot - gi * 3;
  const int g = gbase + gi;
  const int ch = g >> kshift;
  const int ks = g & (P - 1);
  const int kbase = ks * kchunk;
  const int row_base = (bt == 1) ? 128 : 0;
  const int col_base = (bt == 0) ? 0 : 128;
  const bool isdiag = (bt != 2);
  const int tid = threadIdx.x;
  const int lane = tid & 63;

  __shared__ __attribute__((aligned(16))) ushort As[BMP * LDSS];
  __shared__ __attribute__((aligned(16))) ushort Bs[BMP * LDSS];

  f32x4 acc[2][4];
#pragma unroll
  for (int m = 0; m < 2; ++m)
#pragma unroll
    for (int n = 0; n < 4; ++n)
      acc[m][n] = (f32x4){0.f, 0.f, 0.f, 0.f};

  const int wave = tid >> 6;          // 0..7
  const int wr = (wave >> 1) * 32;    // 0,32,64,96
  const int wc = (wave & 1) * 64;     // 0,64

  // staging geometry: rows r0 and r0+64 of the 128-row region, 8 floats at c8.
  // Regions are 128-aligned, so local row r maps directly to row r of src/tgt.
  const int r0 = tid >> 3;          // 0..63
  const int c8 = (tid & 7) * 8;     // 0,8,...,56
  const float* Ab = row_base ? tgt : src;
  const float* Bb = col_base ? tgt : src;
  const float* ap[2];
  const float* bp[2];
#pragma unroll
  for (int p = 0; p < 2; ++p) {
    ap[p] = Ab + ((size_t)(r0 + p * 64) * NCH + ch) * DIM + c8;
    bp[p] = Bb + ((size_t)(r0 + p * 64) * NCH + ch) * DIM + c8;
  }

  f32x4 va[2][2], vb[2][2];
#pragma unroll
  for (int p = 0; p < 2; ++p) {
    va[p][0] = *reinterpret_cast<const f32x4*>(ap[p] + kbase);
    va[p][1] = *reinterpret_cast<const f32x4*>(ap[p] + kbase + 4);
    if (!isdiag) {
      vb[p][0] = *reinterpret_cast<const f32x4*>(bp[p] + kbase);
      vb[p][1] = *reinterpret_cast<const f32x4*>(bp[p] + kbase + 4);
    }
  }

  const int kend = kbase + kchunk;
  for (int k0 = kbase; k0 < kend; k0 += BK) {
    __syncthreads();  // previous iteration's ds_reads done
#pragma unroll
    for (int p = 0; p < 2; ++p) {
      u32x4 wa;
      wa.x = pack_bf2(va[p][0].x, va[p][0].y);
      wa.y = pack_bf2(va[p][0].z, va[p][0].w);
      wa.z = pack_bf2(va[p][1].x, va[p][1].y);
      wa.w = pack_bf2(va[p][1].z, va[p][1].w);
      *reinterpret_cast<u32x4*>(&As[(r0 + p * 64) * LDSS + c8]) = wa;
      if (!isdiag) {
        u32x4 wb;
        wb.x = pack_bf2(vb[p][0].x, vb[p][0].y);
        wb.y = pack_bf2(vb[p][0].z, vb[p][0].w);
        wb.z = pack_bf2(vb[p][1].x, vb[p][1].y);
        wb.w = pack_bf2(vb[p][1].z, vb[p][1].w);
        *reinterpret_cast<u32x4*>(&Bs[(r0 + p * 64) * LDSS + c8]) = wb;
      }
    }
    // issue next K-step's loads NOW; they fly across the MFMA phase
    if (k0 + BK < kend) {
#pragma unroll
      for (int p = 0; p < 2; ++p) {
        va[p][0] = *reinterpret_cast<const f32x4*>(ap[p] + k0 + BK);
        va[p][1] = *reinterpret_cast<const f32x4*>(ap[p] + k0 + BK + 4);
        if (!isdiag) {
          vb[p][0] = *reinterpret_cast<const f32x4*>(bp[p] + k0 + BK);
          vb[p][1] = *reinterpret_cast<const f32x4*>(bp[p] + k0 + BK + 4);
        }
      }
    }
    // write-visibility barrier WITHOUT draining vmcnt
    asm volatile("s_waitcnt lgkmcnt(0)" ::: "memory");
    __builtin_amdgcn_s_barrier();
    asm volatile("" ::: "memory");

    const ushort* Bsrc = isdiag ? As : Bs;
#pragma unroll
    for (int kk = 0; kk < 2; ++kk) {
      const int kb = kk * 32 + (lane >> 4) * 8;
      bf16x8 a[2], b[4];
#pragma unroll
      for (int m = 0; m < 2; ++m)
        a[m] = *reinterpret_cast<const bf16x8*>(
            &As[(wr + m * 16 + (lane & 15)) * LDSS + kb]);
#pragma unroll
      for (int n = 0; n < 4; ++n)
        b[n] = *reinterpret_cast<const bf16x8*>(
            &Bsrc[(wc + n * 16 + (lane & 15)) * LDSS + kb]);
#pragma unroll
      for (int m = 0; m < 2; ++m)
#pragma unroll
        for (int n = 0; n < 4; ++n)
          acc[m][n] = __builtin_amdgcn_mfma_f32_16x16x32_bf16(a[m], b[n],
                                                              acc[m][n], 0, 0, 0);
    }
  }

  // C/D layout (m89): col = lane&15, row = (lane>>4)*4 + reg. Skip mirrors.
  float* gp = Gp + (size_t)(ch * P + ks) * (NROW * NROW);
#pragma unroll
  for (int m = 0; m < 2; ++m)
#pragma unroll
    for (int n = 0; n < 4; ++n) {
      const int grow = row_base + wr + m * 16 + ((lane >> 4) << 2);
      const int gcol = col_base + wc + n * 16 + (lane & 15);
      if ((grow >> 6) > (gcol >> 6)) continue;  // lower-tri mirror: not stored
#pragma unroll
      for (int j = 0; j < 4; ++j)
        gp[(size_t)(grow + j) * NROW + gcol] = acc[m][n][j];
    }
}

// ---------------------------------------------------------------------------
__device__ __forceinline__ float block_sum256(float v, float* sm) {
#pragma unroll
  for (int o = 32; o > 0; o >>= 1) v += __shfl_down(v, o, 64);
  const int lane = threadIdx.x & 63;
  const int w = threadIdx.x >> 6;
  if (lane == 0) sm[w] = v;
  __syncthreads();
  float r = 0.f;
  if (threadIdx.x == 0) r = sm[0] + sm[1] + sm[2] + sm[3];
  __syncthreads();
  return r;  // valid on thread 0
}

// ---------------------------------------------------------------------------
// Fold K-split partials for one (ch,tile) AND produce tile sum + diag trace.
// sums layout: 20 floats/ch: [0..9] tile sums, [10..13] diag-tile traces.
__global__ __launch_bounds__(256) void foldsum_kernel(
    const f32x4* __restrict__ Gp, f32x4* __restrict__ Gf,
    float* __restrict__ sums, int P) {
  const int t = blockIdx.x;
  const int ch = blockIdx.y;
  const int ti = g_TI[t], tj = g_TJ[t];
  const bool isdiag = (ti == tj);
  const int tid = threadIdx.x;
  float s = 0.f, tr = 0.f;
#pragma unroll
  for (int i = 0; i < 4; ++i) {
    const int idx4 = tid * 4 + i;
    const int rrow = idx4 >> 4;       // 0..63
    const int c4 = idx4 & 15;         // 0..15
    const int base_v = (ti * 64 + rrow) * 64 + tj * 16 + c4;
    f32x4 v = Gp[(size_t)(ch * P) * 16384 + base_v];
    for (int p = 1; p < P; ++p) v += Gp[(size_t)(ch * P + p) * 16384 + base_v];
    Gf[(size_t)ch * 16384 + base_v] = v;
    s += (v.x + v.y) + (v.z + v.w);
    if (isdiag) {
      const int cb = c4 * 4;
#pragma unroll
      for (int e = 0; e < 4; ++e)
        if (cb + e == rrow) tr += v[e];
    }
  }
  __shared__ float sm[4];
  float sG = block_sum256(s, sm);
  float sT = block_sum256(tr, sm);
  if (tid == 0) {
    sums[ch * 20 + t] = sG;
    if (isdiag) sums[ch * 20 + 10 + ti] = sT;
  }
}

// ---------------------------------------------------------------------------
// per (tile, ch): w * sign * sum over tile of sum_a exp(-L2/(bw*2^a)).
__global__ __launch_bounds__(256) void mmd_kernel(const float* __restrict__ Gf,
                                                  const float* __restrict__ sums,
                                                  float* __restrict__ partial) {
  const int t = blockIdx.x;
  const int ch = blockIdx.y;
  const int ti = g_TI[t], tj = g_TJ[t];
  const int tid = threadIdx.x;
  const float* g = Gf + (size_t)ch * (NROW * NROW);

  // bandwidth: sum(G) = sum_diag_tiles + 2*sum_offdiag_tiles
  const float* sc = sums + ch * 20;
  float sumG = 0.f;
#pragma unroll
  for (int k = 0; k < NTILE; ++k)
    sumG += (g_TI[k] == g_TJ[k] ? 1.f : 2.f) * sc[k];
  const float trace = (sc[10] + sc[11]) + (sc[12] + sc[13]);
  const float sumL2 = 2.f * NROW * trace - 2.f * sumG;
  const float bw = sumL2 / (float)(NROW * NROW - NROW) * 0.25f;
  float inv[5];
#pragma unroll
  for (int a = 0; a < 5; ++a) inv[a] = -1.f / (bw * (float)(1 << a));

  __shared__ float dA[64], dB[64];
  if (tid < 64) dA[tid] = g[(size_t)(ti * 64 + tid) * (NROW + 1)];
  else if (tid < 128) dB[tid - 64] = g[(size_t)(tj * 64 + (tid - 64)) * (NROW + 1)];
  __syncthreads();

  const int col = tid & 63;
  const int qq = tid >> 6;
  const float dj = dB[col];
  float acc = 0.f;
#pragma unroll 4
  for (int it = 0; it < 16; ++it) {
    const int r = it * 4 + qq;
    const float L2 = dA[r] + dj - 2.f * g[(size_t)(ti * 64 + r) * NROW + tj * 64 + col];
    float kv = 0.f;
#pragma unroll
    for (int a = 0; a < 5; ++a) kv += __expf(L2 * inv[a]);
    acc += kv;
  }
  __shared__ float sm[4];
  float tot = block_sum256(acc, sm);
  if (tid == 0) {
    float w = (ti == tj) ? 1.f : 2.f;                    // off-diag mirror
    float sgn = ((ti >= 2) == (tj >= 2)) ? 1.f : -1.f;   // XX/YY + , XY/YX -
    partial[ch * NTILE + t] = tot * w * sgn;
  }
}

__global__ __launch_bounds__(256) void final_kernel(const float* __restrict__ partial,
                                                    float* __restrict__ out) {
  const int tid = threadIdx.x;
  float v = (tid < NCH * NTILE) ? partial[tid] : 0.f;
  __shared__ float sm[4];
  float tot = block_sum256(v, sm);
  if (tid == 0) out[0] = tot * (1.f / (NCH * 128.f * 128.f));
}

// ---------------------------------------------------------------------------
extern "C" void kernel_launch(void* const* d_in, const int* in_sizes, int n_in,
                              void* d_out, int out_size, void* d_ws, size_t ws_size,
                              hipStream_t stream) {
  const float* src = (const float*)d_in[0];
  const float* tgt = (const float*)d_in[1];
  float* out = (float*)d_out;
  const size_t GSZ = (size_t)NROW * NROW;  // 65536

  int kshift = 0;
  if (ws_size >= (NCH * 9 * GSZ + 512) * sizeof(float)) kshift = 3;
  else if (ws_size >= (NCH * 5 * GSZ + 512) * sizeof(float)) kshift = 2;
  else if (ws_size >= (NCH * 3 * GSZ + 512) * sizeof(float)) kshift = 1;
  const int P = 1 << kshift;

  float* Gp = (float*)d_ws;
  float* Gf = (P > 1) ? Gp + (size_t)NCH * P * GSZ : Gp;  // P==1: alias, fold is copy
  float* sums = Gf + (size_t)NCH * GSZ;                   // NCH*20
  float* partial = sums + NCH * 20;                       // NCH*10

  // XCD-grouped grid: 3 pair-blocks per (ch,ks) group (bijective m204 split)
  const int NG = NCH * P;
  const int q = NG / 8, r8 = NG % 8;
  const int grid = 8 * (q + (r8 ? 1 : 0)) * 3;

  gram_kernel<<<dim3(grid), 512, 0, stream>>>(src, tgt, Gp, kshift, DIM >> kshift);
  foldsum_kernel<<<dim3(NTILE, NCH), 256, 0, stream>>>((const f32x4*)Gp,
                                                       (f32x4*)Gf, sums, P);
  mmd_kernel<<<dim3(NTILE, NCH), 256, 0, stream>>>(Gf, sums, partial);
  final_kernel<<<1, 256, 0, stream>>>(partial, out);
}